// Round 19
// baseline (283.476 us; speedup 1.0000x reference)
//
#include <hip/hip_runtime.h>
#include <math.h>

#define THREADS 256
#define BM 128
#define EPSV 1e-5f
#define C1E 11.023176380641601f   // e^2.4
#define C2E 9.025013499434122f    // e^2.2
#define FP8_SCALE 256.0f          // power-of-2 row scale into e4m3 range
#define INV_SCALE2 1.52587890625e-5f   // 1/65536, exact

typedef float f32x4 __attribute__((ext_vector_type(4)));

// ---------------------------------------------------------------------------
// Kernel A (fp8 path): normalize row, scale by 256, convert to OCP e4m3.
// (R15/R17-proven: absmax 0.0 on the final scalar.)
// ---------------------------------------------------------------------------
__launch_bounds__(THREADS)
__global__ void norm_conv_fp8_kernel(const float* __restrict__ x,
                                     unsigned char* __restrict__ xq, int D) {
    const int row = blockIdx.x;
    const float4* x4 = (const float4*)(x + (size_t)row * D);
    const int tid = threadIdx.x;

    float s = 0.f;
    for (int b = tid * 2; b * 4 < D; b += THREADS * 2) {
        float4 v0 = x4[b];
        float4 v1 = x4[b + 1];
        s += v0.x * v0.x + v0.y * v0.y + v0.z * v0.z + v0.w * v0.w
           + v1.x * v1.x + v1.y * v1.y + v1.z * v1.z + v1.w * v1.w;
    }
#pragma unroll
    for (int off = 32; off > 0; off >>= 1) s += __shfl_down(s, off, 64);
    __shared__ float red[THREADS / 64 + 1];
    if ((tid & 63) == 0) red[tid >> 6] = s;
    __syncthreads();
    if (tid == 0) {
        float tot = 0.f;
#pragma unroll
        for (int w = 0; w < THREADS / 64; ++w) tot += red[w];
        red[THREADS / 64] = FP8_SCALE / fmaxf(sqrtf(tot), 1e-12f);
    }
    __syncthreads();
    const float sc = red[THREADS / 64];

    int2* out = (int2*)(xq + (size_t)row * D);
    for (int b = tid * 2; b * 4 < D; b += THREADS * 2) {
        float4 v0 = x4[b];
        float4 v1 = x4[b + 1];
        int lo = __builtin_amdgcn_cvt_pk_fp8_f32(v0.x * sc, v0.y * sc, 0, 0);
        lo = __builtin_amdgcn_cvt_pk_fp8_f32(v0.z * sc, v0.w * sc, lo, 1);
        int hi = __builtin_amdgcn_cvt_pk_fp8_f32(v1.x * sc, v1.y * sc, 0, 0);
        hi = __builtin_amdgcn_cvt_pk_fp8_f32(v1.z * sc, v1.w * sc, hi, 1);
        int2 o; o.x = lo; o.y = hi;
        out[b >> 1] = o;
    }
}

// Plain inv-norm (fallback path).
__global__ void row_inv_norm_kernel(const float* __restrict__ x,
                                    float* __restrict__ inv_norm, int D) {
    const int row = blockIdx.x;
    const float4* x4 = (const float4*)(x + (size_t)row * D);
    const int nf4 = D >> 2;
    float s = 0.f;
    for (int i = threadIdx.x; i < nf4; i += THREADS) {
        float4 v = x4[i];
        s += v.x * v.x + v.y * v.y + v.z * v.z + v.w * v.w;
    }
#pragma unroll
    for (int off = 32; off > 0; off >>= 1) s += __shfl_down(s, off, 64);
    __shared__ float red[THREADS / 64];
    if ((threadIdx.x & 63) == 0) red[threadIdx.x >> 6] = s;
    __syncthreads();
    if (threadIdx.x == 0) {
        float tot = 0.f;
#pragma unroll
        for (int w = 0; w < THREADS / 64; ++w) tot += red[w];
        inv_norm[row] = 1.0f / fmaxf(sqrtf(tot), 1e-12f);
    }
}

// ---------------------------------------------------------------------------
// Kernel B: SYMMETRIC fp8 Gram — NO-LDS STREAMING K-LOOP (barrier-free).
// The m97-family glds structure plateaued at ~85us across 11 variants
// (single-buf, dbuf, BK sweeps): the barrier-locked phase structure is the
// floor, not the drain (R10/R18 dbuf both neutral). This kernel removes
// the structure: fp8 fragments are 8 CONTIGUOUS bytes/lane (R15/R17-proven
// layout), so each wave loads them DIRECTLY from global. No glds, no
// ds_read, no __syncthreads, zero LDS. A quad-group (4 lanes, same row)
// covers 32 contiguous bytes; a row's 128B line is consumed within one
// BK=128 span -> L1-hit after first touch. Depth-1 register prefetch;
// 8 independent waves/CU hide L2 latency. Epilogue/pr/pc unchanged.
// vals: 0 s_pos_intra 1 cnt_pi 2 s_pos_cross 3 cnt_pc
//       4 DE_neg_intra 5 E_neg_intra 6 DE_neg_cross 7 E_neg_cross
// ---------------------------------------------------------------------------
__launch_bounds__(THREADS, 2)
__global__ void gram_fp8_kernel(const unsigned char* __restrict__ xq,
                                const int* __restrict__ targets,
                                const int* __restrict__ sub,
                                float* __restrict__ pr,
                                float* __restrict__ pc,
                                int D) {
    // Triangular decode: tk = bx*(bx+1)/2 + by, by <= bx.
    const int tk = blockIdx.x;
    int bx = (int)((sqrtf(8.0f * tk + 1.0f) - 1.0f) * 0.5f);
    while ((bx + 1) * (bx + 2) / 2 <= tk) ++bx;
    while (bx * (bx + 1) / 2 > tk) --bx;
    const int by = tk - bx * (bx + 1) / 2;

    const int tid = threadIdx.x;
    const int w = tid >> 6;          // wave 0..3
    const int lane = tid & 63;
    const int wm = w & 1;            // row-half
    const int wn = w >> 1;           // col-half
    const int quad = lane >> 4;
    const int cl = lane & 15;

    const int rowA0 = by * BM;
    const int colB0 = bx * BM;

    // Per-lane fragment stream bases: row r, k-window kb: bytes
    // [r*D + kb + quad*8, +8). Four f-rows per matrix.
    const unsigned char* Ap[4];
    const unsigned char* Bp[4];
#pragma unroll
    for (int f = 0; f < 4; ++f) {
        const int ar = rowA0 + wm * 64 + f * 16 + cl;
        const int br = colB0 + wn * 64 + f * 16 + cl;
        Ap[f] = xq + (size_t)ar * D + quad * 8;
        Bp[f] = xq + (size_t)br * D + quad * 8;
    }

    f32x4 accv[4][4];
#pragma unroll
    for (int i = 0; i < 4; ++i)
#pragma unroll
        for (int j = 0; j < 4; ++j) accv[i][j] = (f32x4)(0.f);

    const int nk = D >> 5;           // K-steps of 32

    // Depth-1 software pipeline: prefetch step s+1 while MFMAing step s.
    long a0[4], b0[4];
#pragma unroll
    for (int f = 0; f < 4; ++f) {
        a0[f] = *(const long*)(Ap[f]);
        b0[f] = *(const long*)(Bp[f]);
    }

#pragma unroll 2
    for (int s = 0; s < nk; ++s) {
        long a1[4], b1[4];
        if (s + 1 < nk) {
            const int kb = (s + 1) << 5;
#pragma unroll
            for (int f = 0; f < 4; ++f) {
                a1[f] = *(const long*)(Ap[f] + kb);
                b1[f] = *(const long*)(Bp[f] + kb);
            }
        }
#pragma unroll
        for (int mi = 0; mi < 4; ++mi)
#pragma unroll
            for (int ni = 0; ni < 4; ++ni)
                accv[mi][ni] = __builtin_amdgcn_mfma_f32_16x16x32_fp8_fp8(
                    a0[mi], b0[ni], accv[mi][ni], 0, 0, 0);
#pragma unroll
        for (int f = 0; f < 4; ++f) { a0[f] = a1[f]; b0[f] = b1[f]; }
    }

    // ---------------- epilogue pass 1: dd + row partials ----------------
    // C/D map: col = cl, row = quad*4 + reg. Dots carry scale 65536.
    int tj[4], sj[4];
#pragma unroll
    for (int ni = 0; ni < 4; ++ni) {
        const int gc = colB0 + wn * 64 + ni * 16 + cl;
        tj[ni] = targets[gc];
        sj[ni] = sub[gc];
    }

#pragma unroll
    for (int mi = 0; mi < 4; ++mi) {
#pragma unroll
        for (int r = 0; r < 4; ++r) {
            const int gi = rowA0 + wm * 64 + mi * 16 + quad * 4 + r;
            const int ti = targets[gi];
            const int si = sub[gi];

            float s0 = 0.f, s1 = 0.f, s2 = 0.f, s3 = 0.f;
            float s4 = 0.f, s5 = 0.f, s6 = 0.f, s7 = 0.f;
#pragma unroll
            for (int ni = 0; ni < 4; ++ni) {
                const int gj = colB0 + wn * 64 + ni * 16 + cl;
                const float d2 =
                    fmaf(-2.0f * INV_SCALE2, accv[mi][ni][r], 2.0f);
                const float dd = sqrtf(fmaxf(d2, 1e-12f));
                accv[mi][ni][r] = dd;          // overwrite: pass 2 reuses
                const bool same = (ti == tj[ni]);
                const bool intra = (si == sj[ni]);
                const bool pos = same && (gi != gj);
                const bool neg = !same;
                const float mg = intra ? 1.4f : 0.7f;
                const float v = fmaxf(dd - mg, 0.f);
                const float e = __expf(-dd);   // e^alpha folded in finalize
                const float de = dd * e;
                if (pos && intra)  { s0 += v;  s1 += 1.f; }
                if (pos && !intra) { s2 += v;  s3 += 1.f; }
                if (neg && intra)  { s4 += de; s5 += e; }
                if (neg && !intra) { s6 += de; s7 += e; }
            }
#pragma unroll
            for (int off = 1; off < 16; off <<= 1) {
                s0 += __shfl_xor(s0, off, 64);
                s1 += __shfl_xor(s1, off, 64);
                s2 += __shfl_xor(s2, off, 64);
                s3 += __shfl_xor(s3, off, 64);
                s4 += __shfl_xor(s4, off, 64);
                s5 += __shfl_xor(s5, off, 64);
                s6 += __shfl_xor(s6, off, 64);
                s7 += __shfl_xor(s7, off, 64);
            }
            if (cl == 0) {
                const int rloc = wm * 64 + mi * 16 + quad * 4 + r;
                float* dst = pr +
                    ((size_t)(blockIdx.x * 2 + wn) * 128 + rloc) * 8;
                float4 p0 = {s0, s1, s2, s3};
                float4 p1 = {s4, s5, s6, s7};
                *(float4*)(dst) = p0;
                *(float4*)(dst + 4) = p1;
            }
        }
    }

    // ---------------- epilogue pass 2: col partials ----------------
    const float om = (bx == by) ? 0.f : 1.f;   // diag tiles: zero col side
#pragma unroll
    for (int ni = 0; ni < 4; ++ni) {
        const int gj = colB0 + wn * 64 + ni * 16 + cl;
        const int tjc = tj[ni];
        const int sjc = sj[ni];
        float s0 = 0.f, s1 = 0.f, s2 = 0.f, s3 = 0.f;
        float s4 = 0.f, s5 = 0.f, s6 = 0.f, s7 = 0.f;
#pragma unroll
        for (int mi = 0; mi < 4; ++mi) {
#pragma unroll
            for (int r = 0; r < 4; ++r) {
                const int gi = rowA0 + wm * 64 + mi * 16 + quad * 4 + r;
                const int ti = targets[gi];     // L1-hot reload
                const int si = sub[gi];
                const float dd = accv[mi][ni][r];
                const bool same = (ti == tjc);
                const bool intra = (si == sjc);
                const bool pos = same && (gi != gj);
                const bool neg = !same;
                const float mg = intra ? 1.4f : 0.7f;
                const float v = fmaxf(dd - mg, 0.f);
                const float e = __expf(-dd);
                const float de = dd * e;
                if (pos && intra)  { s0 += v;  s1 += 1.f; }
                if (pos && !intra) { s2 += v;  s3 += 1.f; }
                if (neg && intra)  { s4 += de; s5 += e; }
                if (neg && !intra) { s6 += de; s7 += e; }
            }
        }
        s0 += __shfl_xor(s0, 16, 64); s0 += __shfl_xor(s0, 32, 64);
        s1 += __shfl_xor(s1, 16, 64); s1 += __shfl_xor(s1, 32, 64);
        s2 += __shfl_xor(s2, 16, 64); s2 += __shfl_xor(s2, 32, 64);
        s3 += __shfl_xor(s3, 16, 64); s3 += __shfl_xor(s3, 32, 64);
        s4 += __shfl_xor(s4, 16, 64); s4 += __shfl_xor(s4, 32, 64);
        s5 += __shfl_xor(s5, 16, 64); s5 += __shfl_xor(s5, 32, 64);
        s6 += __shfl_xor(s6, 16, 64); s6 += __shfl_xor(s6, 32, 64);
        s7 += __shfl_xor(s7, 16, 64); s7 += __shfl_xor(s7, 32, 64);
        if (lane < 16) {
            const int colloc = wn * 64 + ni * 16 + lane;
            float* dst = pc +
                ((size_t)(blockIdx.x * 2 + wm) * 128 + colloc) * 8;
            float4 p0 = {s0 * om, s1 * om, s2 * om, s3 * om};
            float4 p1 = {s4 * om, s5 * om, s6 * om, s7 * om};
            *(float4*)(dst) = p0;
            *(float4*)(dst + 4) = p1;
        }
    }
}

// ---------------------------------------------------------------------------
// Kernel C: gather 64 slices per row, combine ratios, global mean.
// ---------------------------------------------------------------------------
__global__ void finalize_sym_kernel(const float* __restrict__ pr,
                                    const float* __restrict__ pc,
                                    float* __restrict__ out, int N, int nbx) {
    const int tid = threadIdx.x;
    const int rloc16 = tid >> 4;
    const int st = tid & 15;
    const int i = blockIdx.x * 16 + rloc16;
    const int B = i >> 7;
    const int rl = i & 127;
    const int nrow = (nbx - B) * 2;

    float a0 = 0.f, a1 = 0.f, a2 = 0.f, a3 = 0.f;
    float a4 = 0.f, a5 = 0.f, a6 = 0.f, a7 = 0.f;
#pragma unroll
    for (int s4i = 0; s4i < 4; ++s4i) {
        const int sidx = st * 4 + s4i;
        const float* base;
        if (sidx < nrow) {
            const int bxx = B + (sidx >> 1);
            const int t = bxx * (bxx + 1) / 2 + B;
            base = pr + ((size_t)(t * 2 + (sidx & 1)) * 128 + rl) * 8;
        } else {
            const int m = sidx - nrow;
            const int t = B * (B + 1) / 2 + (m >> 1);
            base = pc + ((size_t)(t * 2 + (m & 1)) * 128 + rl) * 8;
        }
        float4 u0 = *(const float4*)(base);
        float4 u1 = *(const float4*)(base + 4);
        a0 += u0.x; a1 += u0.y; a2 += u0.z; a3 += u0.w;
        a4 += u1.x; a5 += u1.y; a6 += u1.z; a7 += u1.w;
    }
#pragma unroll
    for (int off = 1; off < 16; off <<= 1) {
        a0 += __shfl_xor(a0, off, 64);
        a1 += __shfl_xor(a1, off, 64);
        a2 += __shfl_xor(a2, off, 64);
        a3 += __shfl_xor(a3, off, 64);
        a4 += __shfl_xor(a4, off, 64);
        a5 += __shfl_xor(a5, off, 64);
        a6 += __shfl_xor(a6, off, 64);
        a7 += __shfl_xor(a7, off, 64);
    }
    __shared__ float lred[16];
    if (st == 0) {
        const float l = a0 / (a1 + EPSV) + a2 / (a3 + EPSV)
            + (C1E * fmaf(2.4f, a5, -a4)) / (C1E * a5 + EPSV)
            + (C2E * fmaf(2.2f, a7, -a6)) / (C2E * a7 + EPSV);
        lred[rloc16] = l;
    }
    __syncthreads();
    if (tid == 0) {
        float tot = 0.f;
#pragma unroll
        for (int k2 = 0; k2 < 16; ++k2) tot += lred[k2];
        atomicAdd(out, tot / (float)N);
    }
}

// ---------------------------------------------------------------------------
// Fallback path (144 KB ws): fp32 tile GEMM + atomic epilogue (R1, known-good)
// ---------------------------------------------------------------------------
__launch_bounds__(THREADS, 2)
__global__ void dist_loss_kernel(const float* __restrict__ x,
                                 const int* __restrict__ targets,
                                 const int* __restrict__ sub,
                                 const float* __restrict__ inv_norm,
                                 float* __restrict__ acc,
                                 int N, int D) {
    __shared__ float Asf[16][128];
    __shared__ float Bsf[16][128];

    const int nbx = N / 128;
    const int bx = blockIdx.x % nbx;
    const int by = blockIdx.x / nbx;
    const int tid = threadIdx.x;
    const int tx = tid & 15;
    const int ty = tid >> 4;
    const int rowA0 = by * 128;
    const int colB0 = bx * 128;
    const float* Abase = x + (size_t)rowA0 * D;
    const float* Bbase = x + (size_t)colB0 * D;

    float accv[8][8];
#pragma unroll
    for (int r = 0; r < 8; ++r)
#pragma unroll
        for (int c = 0; c < 8; ++c) accv[r][c] = 0.f;

    for (int kb = 0; kb < D; kb += 16) {
#pragma unroll
        for (int l = 0; l < 2; ++l) {
            const int f = tid + l * THREADS;
            const int row = f >> 2;
            const int kq = (f & 3) << 2;
            float4 va = *(const float4*)(Abase + (size_t)row * D + kb + kq);
            float4 vb = *(const float4*)(Bbase + (size_t)row * D + kb + kq);
            Asf[kq + 0][row] = va.x; Asf[kq + 1][row] = va.y;
            Asf[kq + 2][row] = va.z; Asf[kq + 3][row] = va.w;
            Bsf[kq + 0][row] = vb.x; Bsf[kq + 1][row] = vb.y;
            Bsf[kq + 2][row] = vb.z; Bsf[kq + 3][row] = vb.w;
        }
        __syncthreads();
#pragma unroll
        for (int k = 0; k < 16; ++k) {
            float4 a0 = *(const float4*)&Asf[k][ty * 8];
            float4 a1 = *(const float4*)&Asf[k][ty * 8 + 4];
            float4 b0 = *(const float4*)&Bsf[k][tx * 8];
            float4 b1 = *(const float4*)&Bsf[k][tx * 8 + 4];
            float ar[8] = {a0.x, a0.y, a0.z, a0.w, a1.x, a1.y, a1.z, a1.w};
            float br[8] = {b0.x, b0.y, b0.z, b0.w, b1.x, b1.y, b1.z, b1.w};
#pragma unroll
            for (int r = 0; r < 8; ++r)
#pragma unroll
                for (int c = 0; c < 8; ++c)
                    accv[r][c] = fmaf(ar[r], br[c], accv[r][c]);
        }
        __syncthreads();
    }

    const int row_base = rowA0 + ty * 8;
    const int col_base = colB0 + tx * 8;
    int tjc[8], sjc[8];
    float invj[8];
#pragma unroll
    for (int c = 0; c < 8; ++c) {
        tjc[c] = targets[col_base + c];
        sjc[c] = sub[col_base + c];
        invj[c] = inv_norm[col_base + c];
    }
#pragma unroll
    for (int r = 0; r < 8; ++r) {
        const int gi = row_base + r;
        const int ti = targets[gi];
        const int si = sub[gi];
        const float invi = inv_norm[gi];
        float s0 = 0.f, s1 = 0.f, s2 = 0.f, s3 = 0.f;
        float s4 = 0.f, s5 = 0.f, s6 = 0.f, s7 = 0.f;
#pragma unroll
        for (int c = 0; c < 8; ++c) {
            const int gj = col_base + c;
            const float dot = accv[r][c] * invi * invj[c];
            const float dd = sqrtf(fmaxf(2.f - 2.f * dot, 1e-12f));
            const bool same = (ti == tjc[c]);
            const bool intra = (si == sjc[c]);
            const bool pos = same && (gi != gj);
            const bool neg = !same;
            const float df = (intra ? 2.4f : 2.2f) - dd;
            const float wgt = __expf(df);
            const float v = fmaxf(dd - (intra ? 1.4f : 0.7f), 0.f);
            if (pos && intra)  { s0 += v; s1 += 1.f; }
            if (pos && !intra) { s2 += v; s3 += 1.f; }
            if (neg && intra)  { s4 += df * wgt; s5 += wgt; }
            if (neg && !intra) { s6 += df * wgt; s7 += wgt; }
        }
#pragma unroll
        for (int off = 1; off < 16; off <<= 1) {
            s0 += __shfl_xor(s0, off, 64);
            s1 += __shfl_xor(s1, off, 64);
            s2 += __shfl_xor(s2, off, 64);
            s3 += __shfl_xor(s3, off, 64);
            s4 += __shfl_xor(s4, off, 64);
            s5 += __shfl_xor(s5, off, 64);
            s6 += __shfl_xor(s6, off, 64);
            s7 += __shfl_xor(s7, off, 64);
        }
        if (tx == 0) {
            float* a = acc + (size_t)gi * 8;
            atomicAdd(a + 0, s0); atomicAdd(a + 1, s1);
            atomicAdd(a + 2, s2); atomicAdd(a + 3, s3);
            atomicAdd(a + 4, s4); atomicAdd(a + 5, s5);
            atomicAdd(a + 6, s6); atomicAdd(a + 7, s7);
        }
    }
}

__global__ void finalize_kernel(const float* __restrict__ acc,
                                float* __restrict__ out, int N) {
    float s = 0.f;
    for (int i = threadIdx.x; i < N; i += THREADS) {
        const float* a = acc + (size_t)i * 8;
        s += a[0] / (a[1] + EPSV) + a[2] / (a[3] + EPSV)
           + a[4] / (a[5] + EPSV) + a[6] / (a[7] + EPSV);
    }
#pragma unroll
    for (int off = 32; off > 0; off >>= 1) s += __shfl_down(s, off, 64);
    __shared__ float red[THREADS / 64];
    if ((threadIdx.x & 63) == 0) red[threadIdx.x >> 6] = s;
    __syncthreads();
    if (threadIdx.x == 0) {
        float tot = 0.f;
#pragma unroll
        for (int w = 0; w < THREADS / 64; ++w) tot += red[w];
        out[0] = tot / (float)N;
    }
}

// ---------------------------------------------------------------------------
extern "C" void kernel_launch(void* const* d_in, const int* in_sizes, int n_in,
                              void* d_out, int out_size, void* d_ws, size_t ws_size,
                              hipStream_t stream) {
    const float* x = (const float*)d_in[0];
    const int* targets = (const int*)d_in[1];
    const int* sub = (const int*)d_in[2];
    const int N = in_sizes[1];
    const int D = in_sizes[0] / N;

    const int nbx = N / BM;
    const int T = nbx * (nbx + 1) / 2;
    const size_t sliceB = (size_t)T * 2 * 128 * 8 * sizeof(float);
    const size_t need = (size_t)N * D + 2 * sliceB;   // fp8: N*D bytes

    if (ws_size >= need) {
        unsigned char* xq = (unsigned char*)d_ws;     // N*D fp8
        float* pr = (float*)((char*)d_ws + (size_t)N * D);
        float* pc = pr + (size_t)T * 2 * 128 * 8;

        hipMemsetAsync(d_out, 0, sizeof(float), stream);
        norm_conv_fp8_kernel<<<N, THREADS, 0, stream>>>(x, xq, D);
        gram_fp8_kernel<<<T, THREADS, 0, stream>>>(xq, targets, sub,
                                                   pr, pc, D);
        finalize_sym_kernel<<<N / 16, THREADS, 0, stream>>>(
            pr, pc, (float*)d_out, N, nbx);
    } else {
        // Fallback (144 KB ws): fp32 path, known-good from round 1.
        float* inv_norm = (float*)d_ws;
        float* acc = inv_norm + N;
        hipMemsetAsync(acc, 0, (size_t)N * 8 * sizeof(float), stream);
        row_inv_norm_kernel<<<N, THREADS, 0, stream>>>(x, inv_norm, D);
        dist_loss_kernel<<<nbx * nbx, THREADS, 0, stream>>>(
            x, targets, sub, inv_norm, acc, N, D);
        finalize_kernel<<<1, THREADS, 0, stream>>>(acc, (float*)d_out, N);
    }
}